// Round 9
// baseline (244.971 us; speedup 1.0000x reference)
//
#include <hip/hip_runtime.h>
#include <hip/hip_bf16.h>

// GINConv: out = relu(((1+eps)x + scatter_sum(x[src]->dst)) @ W1 + b1) @ W2 + b2
#define N_NODES 50000
#define F_IN    128
#define F_HID   512
#define N_EDGES 800000
// Binning: 4 sub-bins per node (one per edge-quarter "replica"), 32 slots each
// (lambda=4; Poisson(4)>32 ~ 1e-20, and writes are clamped). NO global atomics:
// ranks come from LDS atomics inside bin_edges.
#define SUB_CAP 32
#define NRANGES 256
#define RSIZE   196   // 256*196 = 50176 >= 50000

typedef __bf16 bf16x2 __attribute__((ext_vector_type(2)));
typedef __bf16 bf16x4 __attribute__((ext_vector_type(4)));
typedef __bf16 bf16x8 __attribute__((ext_vector_type(8)));
typedef float  f32x4  __attribute__((ext_vector_type(4)));

// ---------------- prep: x->bf16 | W1,W2 -> MFMA B-fragment order ------------------------
// B-fragment layout (HW-verified): lane holds B[k=(lane>>4)*8+j][n=lane&15].
#define NB_X 6250   // 50000*128/4/256
#define NB_W 32     // 8192 fragment-slots / 256
__global__ __launch_bounds__(256) void prep(const float* __restrict__ x,
                                            const float* __restrict__ W1,
                                            const float* __restrict__ W2,
                                            __bf16* __restrict__ xb,
                                            __bf16* __restrict__ w1f,
                                            __bf16* __restrict__ w2f) {
    int b = blockIdx.x, tid = threadIdx.x;
    if (b < NB_X) {
        int i = b * 256 + tid;
        float4 v = ((const float4*)x)[i];
        bf16x4 o = {(__bf16)v.x, (__bf16)v.y, (__bf16)v.z, (__bf16)v.w};
        ((bf16x4*)xb)[i] = o;
    } else if (b < NB_X + NB_W) {
        int t = (b - NB_X) * 256 + tid;
        int lane = t & 63, kk = (t >> 6) & 3, nt = (t >> 8) & 7, c = (t >> 11) & 3;
        int q = lane >> 4, l16 = lane & 15;
        bf16x8 o;
        #pragma unroll
        for (int j = 0; j < 8; ++j)
            o[j] = (__bf16)W1[(kk * 32 + q * 8 + j) * F_HID + c * 128 + nt * 16 + l16];
        *(bf16x8*)(w1f + (size_t)t * 8) = o;
    } else {
        int t = (b - NB_X - NB_W) * 256 + tid;
        int lane = t & 63, kk = (t >> 6) & 3, nt = (t >> 8) & 7, c = (t >> 11) & 3;
        int q = lane >> 4, l16 = lane & 15;
        bf16x8 o;
        #pragma unroll
        for (int j = 0; j < 8; ++j)
            o[j] = (__bf16)W2[(c * 128 + kk * 32 + q * 8 + j) * F_IN + nt * 16 + l16];
        *(bf16x8*)(w2f + (size_t)t * 8) = o;
    }
}

// ---------------- bin_edges: dst-range scan + LDS-atomic ranking (no global atomics) ----
// Block = (range, replica): range rb covers dst in [rb*196, rb*196+196); replica r scans
// edge quarter [r*200K, (r+1)*200K). Each block rescans its quarter's dst array (L2-hot,
// int4 loads), keeps in-range edges, ranks via LDS atomicAdd, writes src into the
// node's sub-bin r. Counts written plainly at the end (no pre-zeroing needed anywhere).
__global__ __launch_bounds__(256) void bin_edges(const int* __restrict__ ei,
                                                 int* __restrict__ counts4,
                                                 int* __restrict__ slots) {
    __shared__ int cnt[RSIZE];
    const int range = blockIdx.x >> 2;
    const int rep   = blockIdx.x & 3;
    const int lo    = range * RSIZE;

    for (int t = threadIdx.x; t < RSIZE; t += 256) cnt[t] = 0;
    __syncthreads();

    const int ebeg = rep * (N_EDGES / 4);
    const int4* dstv = (const int4*)(ei + N_EDGES + ebeg);
    const int niter = (N_EDGES / 4) / 4;          // 50000 int4 per quarter
    for (int i = threadIdx.x; i < niter; i += 256) {
        int4 d4 = dstv[i];
        #pragma unroll
        for (int k = 0; k < 4; ++k) {
            int d = (&d4.x)[k];
            unsigned local = (unsigned)(d - lo);
            if (local < RSIZE) {
                int e = ebeg + i * 4 + k;
                int s = ei[e];
                int p = atomicAdd(&cnt[local], 1);
                slots[(d << 7) + (rep << 5) + (p & (SUB_CAP - 1))] = s;
            }
        }
    }
    __syncthreads();

    for (int t = threadIdx.x; t < RSIZE; t += 256)
        counts4[(lo + t) * 4 + rep] = cnt[t];
}

// ---------------- gather-sum v4: quad q drains sub-bin q -------------------------------
// One wave per node. Lane=(q,l16): l16*8 = 16B feature chunk; quad q walks sub-bin q
// (lambda=4, 2-unrolled). Cross-quad reduction: 2x shfl_xor; q==0 writes the bf16 row.
__global__ __launch_bounds__(256) void gather_agg(const __bf16* __restrict__ xb,
                                                  const int* __restrict__ counts4,
                                                  const int* __restrict__ slots,
                                                  const float* __restrict__ eps,
                                                  __bf16* __restrict__ agg) {
    int node = blockIdx.x * 4 + (threadIdx.x >> 6);
    int lane = threadIdx.x & 63;
    int q = lane >> 4, l16 = lane & 15;
    if (node >= N_NODES) return;
    const float s = 1.0f + eps[0];

    int cnt = counts4[node * 4 + q];              // quad-uniform broadcast load
    cnt = cnt < SUB_CAP ? cnt : SUB_CAP;
    const int* bin = slots + (node << 7) + (q << 5);

    float acc[8];
    #pragma unroll
    for (int i = 0; i < 8; ++i) acc[i] = 0.0f;
    if (q == 0) {
        bf16x8 self = *(const bf16x8*)(xb + (size_t)node * F_IN + l16 * 8);
        #pragma unroll
        for (int i = 0; i < 8; ++i) acc[i] = (float)self[i] * s;
    }

    int j = 0;
    for (; j + 1 < cnt; j += 2) {
        int s0 = bin[j];
        int s1 = bin[j + 1];
        bf16x8 v0 = *(const bf16x8*)(xb + (size_t)s0 * F_IN + l16 * 8);
        bf16x8 v1 = *(const bf16x8*)(xb + (size_t)s1 * F_IN + l16 * 8);
        #pragma unroll
        for (int i = 0; i < 8; ++i) acc[i] += (float)v0[i] + (float)v1[i];
    }
    if (j < cnt) {
        bf16x8 v = *(const bf16x8*)(xb + (size_t)bin[j] * F_IN + l16 * 8);
        #pragma unroll
        for (int i = 0; i < 8; ++i) acc[i] += (float)v[i];
    }

    #pragma unroll
    for (int i = 0; i < 8; ++i) {
        acc[i] += __shfl_xor(acc[i], 16);
        acc[i] += __shfl_xor(acc[i], 32);
    }
    if (q == 0) {
        bf16x8 o;
        #pragma unroll
        for (int i = 0; i < 8; ++i) o[i] = (__bf16)acc[i];
        *(bf16x8*)(agg + (size_t)node * F_IN + l16 * 8) = o;
    }
}

// ---------------- fused MLP: out = relu(agg@W1+b1)@W2+b2 -------------------------------
// 32 rows/block. Weights in B-fragment order from global (L2-hot), h through 8 KB LDS in
// A-fragment order, 2 barriers/chunk.
__global__ __launch_bounds__(256) void fused_mlp(const __bf16* __restrict__ A,
                                                 const __bf16* __restrict__ w1f,
                                                 const __bf16* __restrict__ w2f,
                                                 const float* __restrict__ b1,
                                                 const float* __restrict__ b2,
                                                 float* __restrict__ out) {
    __shared__ __attribute__((aligned(16))) __bf16 Hb[4096];   // 8 KB, A-frag order

    const int tid  = threadIdx.x;
    const int wave = tid >> 6;
    const int lane = tid & 63;
    const int q = lane >> 4, l16 = lane & 15;
    const int m0 = blockIdx.x * 32;

    bf16x8 a_reg[2][4];
    #pragma unroll
    for (int mi = 0; mi < 2; ++mi) {
        int m = m0 + mi * 16 + l16;
        #pragma unroll
        for (int kk = 0; kk < 4; ++kk) {
            if (m < N_NODES)
                a_reg[mi][kk] = *(const bf16x8*)(A + (size_t)m * F_IN + kk * 32 + q * 8);
            else {
                __bf16 z = (__bf16)0.0f;
                a_reg[mi][kk] = (bf16x8){z, z, z, z, z, z, z, z};
            }
        }
    }

    f32x4 acc_o[2][2];
    #pragma unroll
    for (int ni = 0; ni < 2; ++ni) {
        float bv = b2[wave * 32 + ni * 16 + l16];
        f32x4 b4 = {bv, bv, bv, bv};
        acc_o[0][ni] = b4;
        acc_o[1][ni] = b4;
    }

    for (int c = 0; c < 4; ++c) {
        f32x4 acc_h[2][2];
        #pragma unroll
        for (int ni = 0; ni < 2; ++ni) {
            float bv = b1[c * 128 + wave * 32 + ni * 16 + l16];
            f32x4 b4 = {bv, bv, bv, bv};
            acc_h[0][ni] = b4;
            acc_h[1][ni] = b4;
        }
        #pragma unroll
        for (int kk = 0; kk < 4; ++kk) {
            bf16x8 bw[2];
            #pragma unroll
            for (int ni = 0; ni < 2; ++ni)
                bw[ni] = *(const bf16x8*)(w1f +
                    ((size_t)((c * 8 + wave * 2 + ni) * 4 + kk) << 9) + lane * 8);
            #pragma unroll
            for (int mi = 0; mi < 2; ++mi)
                #pragma unroll
                for (int ni = 0; ni < 2; ++ni)
                    acc_h[mi][ni] = __builtin_amdgcn_mfma_f32_16x16x32_bf16(
                        a_reg[mi][kk], bw[ni], acc_h[mi][ni], 0, 0, 0);
        }
        // relu -> Hb in A-fragment order (C elem (row=mi*16+q*4+r, col=wave*32+ni*16+l16))
        #pragma unroll
        for (int mi = 0; mi < 2; ++mi)
            #pragma unroll
            for (int ni = 0; ni < 2; ++ni)
                #pragma unroll
                for (int r = 0; r < 4; ++r)
                    Hb[(((mi * 4 + wave) * 64 + (ni * 2 + (l16 >> 3)) * 16 + q * 4 + r) << 3)
                       + (l16 & 7)] = (__bf16)fmaxf(acc_h[mi][ni][r], 0.0f);
        __syncthreads();

        #pragma unroll
        for (int kk = 0; kk < 4; ++kk) {
            bf16x8 am[2], bw[2];
            #pragma unroll
            for (int mi = 0; mi < 2; ++mi)
                am[mi] = *(const bf16x8*)&Hb[((mi * 4 + kk) * 64 + lane) << 3];
            #pragma unroll
            for (int ni = 0; ni < 2; ++ni)
                bw[ni] = *(const bf16x8*)(w2f +
                    ((size_t)((c * 8 + wave * 2 + ni) * 4 + kk) << 9) + lane * 8);
            #pragma unroll
            for (int mi = 0; mi < 2; ++mi)
                #pragma unroll
                for (int ni = 0; ni < 2; ++ni)
                    acc_o[mi][ni] = __builtin_amdgcn_mfma_f32_16x16x32_bf16(
                        am[mi], bw[ni], acc_o[mi][ni], 0, 0, 0);
        }
        __syncthreads();
    }

    #pragma unroll
    for (int mi = 0; mi < 2; ++mi)
        #pragma unroll
        for (int ni = 0; ni < 2; ++ni)
            #pragma unroll
            for (int r = 0; r < 4; ++r) {
                int m = m0 + mi * 16 + q * 4 + r;
                if (m < N_NODES)
                    out[(size_t)m * F_IN + wave * 32 + ni * 16 + l16] = acc_o[mi][ni][r];
            }
}

extern "C" void kernel_launch(void* const* d_in, const int* in_sizes, int n_in,
                              void* d_out, int out_size, void* d_ws, size_t ws_size,
                              hipStream_t stream) {
    const float* x   = (const float*)d_in[0];
    const int*   ei  = (const int*)d_in[1];
    const float* W1  = (const float*)d_in[2];
    const float* b1  = (const float*)d_in[3];
    const float* W2  = (const float*)d_in[4];
    const float* b2  = (const float*)d_in[5];
    const float* eps = (const float*)d_in[6];
    float* out = (float*)d_out;

    // ws layout (~53 MB):
    char* ws = (char*)d_ws;
    __bf16* xb   = (__bf16*)ws;                    // 12.8e6 B
    __bf16* agg  = (__bf16*)(ws + 12800000);       // 12.8e6 B
    __bf16* w1f  = (__bf16*)(ws + 25600000);       // 131072 B
    __bf16* w2f  = (__bf16*)(ws + 25800000);       // 131072 B
    int*    counts4 = (int*)(ws + 26000000);       // 50176*4*4 = 802816 B
    int*    slots   = (int*)(ws + 27000000);       // 50176*128*4 = 25.7e6 B

    prep<<<NB_X + 2 * NB_W, 256, 0, stream>>>(x, W1, W2, xb, w1f, w2f);
    bin_edges<<<NRANGES * 4, 256, 0, stream>>>(ei, counts4, slots);
    gather_agg<<<(N_NODES + 3) / 4, 256, 0, stream>>>(xb, counts4, slots, eps, agg);
    fused_mlp<<<(N_NODES + 31) / 32, 256, 0, stream>>>(agg, w1f, w2f, b1, b2, out);
}